// Round 1
// baseline (273.631 us; speedup 1.0000x reference)
//
#include <hip/hip_runtime.h>
#include <math.h>

#define BATCH 16
#define N_ROIS 1000
#define NUM_CLASSES 81
#define DET_MAX 100
#define MIN_CONF 0.7f
#define NMS_THRESH 0.3f

// ---------------- Kernel A: per-ROI argmax + box refine + clip ----------------
__global__ __launch_bounds__(256) void refine_kernel(
    const float* __restrict__ rois, const float* __restrict__ probs,
    const float* __restrict__ deltas, const float* __restrict__ window,
    float* __restrict__ ws_box, float* __restrict__ ws_score, int* __restrict__ ws_cls)
{
    int idx = blockIdx.x * blockDim.x + threadIdx.x;
    if (idx >= BATCH * N_ROIS) return;
    int b = idx / N_ROIS;

    // argmax over 81 class probs (first max wins, matching jnp.argmax)
    const float* p = probs + (size_t)idx * NUM_CLASSES;
    int best = 0;
    float bs = p[0];
    for (int c = 1; c < NUM_CLASSES; ++c) {
        float v = p[c];
        if (v > bs) { bs = v; best = c; }
    }

    // gather the selected delta row, scale by BBOX_STD
    const float* d = deltas + ((size_t)idx * NUM_CLASSES + best) * 4;
    float dy = d[0] * 0.1f, dx = d[1] * 0.1f, dh = d[2] * 0.2f, dw = d[3] * 0.2f;

    const float* r = rois + (size_t)idx * 4;
    float y1 = r[0], x1 = r[1], y2 = r[2], x2 = r[3];
    float h = y2 - y1, w = x2 - x1;
    float cy = y1 + 0.5f * h, cx = x1 + 0.5f * w;
    cy += dy * h;
    cx += dx * w;
    h *= expf(dh);
    w *= expf(dw);
    float ny1 = cy - 0.5f * h;
    float nx1 = cx - 0.5f * w;
    float ny2 = ny1 + h;   // matches reference: y2 = y1 + h
    float nx2 = nx1 + w;

    const float* win = window + b * 4;
    float wy1 = win[0], wx1 = win[1], wy2 = win[2], wx2 = win[3];
    ny1 = fminf(fmaxf(ny1, wy1), wy2);
    nx1 = fminf(fmaxf(nx1, wx1), wx2);
    ny2 = fminf(fmaxf(ny2, wy1), wy2);
    nx2 = fminf(fmaxf(nx2, wx1), wx2);

    bool keep = (best > 0) && (bs >= MIN_CONF);

    ws_box[idx * 4 + 0] = ny1;
    ws_box[idx * 4 + 1] = nx1;
    ws_box[idx * 4 + 2] = ny2;
    ws_box[idx * 4 + 3] = nx2;
    ws_score[idx] = keep ? bs : -1.0f;
    ws_cls[idx] = best;
}

// ---------------- Kernel B: per-batch NMS + top-K ----------------
__device__ inline float iou_f(const float* a, const float* b) {
    float y1 = fmaxf(a[0], b[0]);
    float x1 = fmaxf(a[1], b[1]);
    float y2 = fminf(a[2], b[2]);
    float x2 = fminf(a[3], b[3]);
    float inter = fmaxf(y2 - y1, 0.0f) * fmaxf(x2 - x1, 0.0f);
    float aa = (a[2] - a[0]) * (a[3] - a[1]);
    float ab = (b[2] - b[0]) * (b[3] - b[1]);
    float uni = aa + ab - inter;
    return inter / fmaxf(uni, 1e-10f);
}

__global__ __launch_bounds__(256) void nms_topk_kernel(
    const float* __restrict__ ws_box, const float* __restrict__ ws_score,
    const int* __restrict__ ws_cls, float* __restrict__ out)
{
    int b = blockIdx.x;
    int tid = threadIdx.x;

    __shared__ float s_box[N_ROIS][4];
    __shared__ float s_sc[N_ROIS];
    __shared__ short s_cls[N_ROIS];
    __shared__ short s_list[N_ROIS];          // class-bucketed candidate indices
    __shared__ unsigned char s_kept[N_ROIS];
    __shared__ unsigned char s_alive[N_ROIS];
    __shared__ int s_cnt[NUM_CLASSES];
    __shared__ int s_off[NUM_CLASSES];

    // zero this batch's output (d_out is poisoned before every replay)
    for (int i = tid; i < DET_MAX * 6; i += blockDim.x)
        out[(size_t)b * DET_MAX * 6 + i] = 0.0f;

    const float* wb = ws_box + (size_t)b * N_ROIS * 4;
    for (int i = tid; i < N_ROIS; i += blockDim.x) {
        s_box[i][0] = wb[i * 4 + 0];
        s_box[i][1] = wb[i * 4 + 1];
        s_box[i][2] = wb[i * 4 + 2];
        s_box[i][3] = wb[i * 4 + 3];
        float sc = ws_score[b * N_ROIS + i];
        s_sc[i] = sc;
        s_cls[i] = (short)ws_cls[b * N_ROIS + i];
        s_kept[i] = 0;
        s_alive[i] = (sc >= 0.0f) ? 1 : 0;
    }
    if (tid < NUM_CLASSES) s_cnt[tid] = 0;
    __syncthreads();

    // count candidates per class
    for (int i = tid; i < N_ROIS; i += blockDim.x)
        if (s_sc[i] >= 0.0f) atomicAdd(&s_cnt[s_cls[i]], 1);
    __syncthreads();

    if (tid == 0) {
        int acc = 0;
        for (int c = 0; c < NUM_CLASSES; ++c) { s_off[c] = acc; acc += s_cnt[c]; }
    }
    __syncthreads();
    if (tid < NUM_CLASSES) s_cnt[tid] = 0;
    __syncthreads();

    // scatter candidate indices into class buckets (order within bucket irrelevant;
    // the greedy selection below re-establishes (score desc, idx asc) order)
    for (int i = tid; i < N_ROIS; i += blockDim.x) {
        if (s_sc[i] >= 0.0f) {
            int c = s_cls[i];
            int p = atomicAdd(&s_cnt[c], 1);
            s_list[s_off[c] + p] = (short)i;
        }
    }
    __syncthreads();

    // per-class greedy NMS: thread c owns class c (class 0 has no candidates)
    if (tid >= 1 && tid < NUM_CLASSES) {
        int beg = s_off[tid];
        int m = s_cnt[tid];
        int kept_cnt = 0;
        while (kept_cnt < DET_MAX) {
            // select highest-score alive candidate; tie -> lowest index
            // (equals reference's stable argsort(-sc) traversal order)
            float best = -1.0f;
            int bi = -1;
            for (int k = 0; k < m; ++k) {
                int i = s_list[beg + k];
                if (s_alive[i]) {
                    float sc = s_sc[i];
                    if (sc > best || (sc == best && (unsigned)i < (unsigned)bi)) {
                        best = sc; bi = i;
                    }
                }
            }
            if (bi < 0) break;
            s_kept[bi] = 1;
            s_alive[bi] = 0;   // explicitly retire (degenerate box self-IoU may be 0)
            ++kept_cnt;
            float bx0 = s_box[bi][0], bx1 = s_box[bi][1], bx2 = s_box[bi][2], bx3 = s_box[bi][3];
            float bxa[4] = {bx0, bx1, bx2, bx3};
            for (int k = 0; k < m; ++k) {
                int i = s_list[beg + k];
                if (s_alive[i]) {
                    if (iou_f(bxa, s_box[i]) > NMS_THRESH) s_alive[i] = 0;
                }
            }
        }
    }
    __syncthreads();

    // top-DET_MAX by (score desc, idx asc) over kept detections == lax.top_k on sf
    for (int i = tid; i < N_ROIS; i += blockDim.x) {
        if (!s_kept[i]) continue;
        float sc = s_sc[i];
        int rank = 0;
        for (int j = 0; j < N_ROIS; ++j) {
            if (s_kept[j]) {
                float sj = s_sc[j];
                if (sj > sc || (sj == sc && j < i)) ++rank;
            }
        }
        if (rank < DET_MAX) {
            float* o = out + (size_t)b * DET_MAX * 6 + rank * 6;
            o[0] = s_box[i][0];
            o[1] = s_box[i][1];
            o[2] = s_box[i][2];
            o[3] = s_box[i][3];
            o[4] = (float)s_cls[i];
            o[5] = sc;
        }
    }
}

extern "C" void kernel_launch(void* const* d_in, const int* in_sizes, int n_in,
                              void* d_out, int out_size, void* d_ws, size_t ws_size,
                              hipStream_t stream) {
    const float* rois      = (const float*)d_in[0];
    const float* fpn_class = (const float*)d_in[1];
    const float* fpn_bbox  = (const float*)d_in[2];
    const float* window    = (const float*)d_in[3];
    float* out = (float*)d_out;

    // workspace layout: boxes | scores | class ids  (384 KB total)
    float* ws_box   = (float*)d_ws;                       // BATCH*N_ROIS*4
    float* ws_score = ws_box + (size_t)BATCH * N_ROIS * 4; // BATCH*N_ROIS
    int*   ws_cls   = (int*)(ws_score + (size_t)BATCH * N_ROIS);

    int total = BATCH * N_ROIS;
    refine_kernel<<<(total + 255) / 256, 256, 0, stream>>>(
        rois, fpn_class, fpn_bbox, window, ws_box, ws_score, ws_cls);
    nms_topk_kernel<<<BATCH, 256, 0, stream>>>(ws_box, ws_score, ws_cls, out);
}

// Round 2
// 94.992 us; speedup vs baseline: 2.8806x; 2.8806x over previous
//
#include <hip/hip_runtime.h>
#include <math.h>

#define BATCH 16
#define N_ROIS 1000
#define NUM_CLASSES 81
#define DET_MAX 100
#define MIN_CONF 0.7f
#define NMS_THRESH 0.3f

#define ROI_TILE 128          // ROIs per block in refine kernel
#define CMAX N_ROIS           // max candidates per batch

// ---------------- Kernel A: per-ROI argmax + box refine + clip ----------------
// Coalesced: stage a 128-ROI x 81-class prob tile through LDS (40.5 KB),
// then per-thread argmax from LDS. Arithmetic identical to R1 (absmax 0.0).
__global__ __launch_bounds__(256) void refine_v2(
    const float* __restrict__ rois, const float* __restrict__ probs,
    const float* __restrict__ deltas, const float* __restrict__ window,
    float* __restrict__ ws_box, float* __restrict__ ws_score, int* __restrict__ ws_cls)
{
    __shared__ float s_probs[ROI_TILE * NUM_CLASSES];   // 128*81*4 = 40.5 KB

    const int tile = blockIdx.x;            // 125 blocks (16000/128)
    const int base_roi = tile * ROI_TILE;

    // coalesced float4 staging: 128*81/4 = 2592 float4, base byte offset
    // base_roi*324 is divisible by 16 since base_roi is a multiple of 128.
    const float4* src = (const float4*)(probs + (size_t)base_roi * NUM_CLASSES);
    float4* dst = (float4*)s_probs;
    for (int i = threadIdx.x; i < ROI_TILE * NUM_CLASSES / 4; i += 256)
        dst[i] = src[i];
    __syncthreads();

    if (threadIdx.x < ROI_TILE) {
        const int idx = base_roi + threadIdx.x;   // flat ROI id, < 16000
        const int b = idx / N_ROIS;

        // argmax over 81 class probs (first max wins, matching jnp.argmax)
        const float* p = s_probs + threadIdx.x * NUM_CLASSES;
        int best = 0;
        float bs = p[0];
        for (int c = 1; c < NUM_CLASSES; ++c) {
            float v = p[c];
            if (v > bs) { bs = v; best = c; }
        }

        // gather the selected delta row (16B-aligned float4), scale by BBOX_STD
        const float4 dd = ((const float4*)deltas)[(size_t)idx * NUM_CLASSES + best];
        float dy = dd.x * 0.1f, dx = dd.y * 0.1f, dh = dd.z * 0.2f, dw = dd.w * 0.2f;

        const float4 rr = ((const float4*)rois)[idx];
        float y1 = rr.x, x1 = rr.y, y2 = rr.z, x2 = rr.w;
        float h = y2 - y1, w = x2 - x1;
        float cy = y1 + 0.5f * h, cx = x1 + 0.5f * w;
        cy += dy * h;
        cx += dx * w;
        h *= expf(dh);
        w *= expf(dw);
        float ny1 = cy - 0.5f * h;
        float nx1 = cx - 0.5f * w;
        float ny2 = ny1 + h;   // matches reference: y2 = y1 + h
        float nx2 = nx1 + w;

        const float* win = window + b * 4;
        float wy1 = win[0], wx1 = win[1], wy2 = win[2], wx2 = win[3];
        ny1 = fminf(fmaxf(ny1, wy1), wy2);
        nx1 = fminf(fmaxf(nx1, wx1), wx2);
        ny2 = fminf(fmaxf(ny2, wy1), wy2);
        nx2 = fminf(fmaxf(nx2, wx1), wx2);

        bool keep = (best > 0) && (bs >= MIN_CONF);

        float4* wbx = (float4*)ws_box;
        wbx[idx] = make_float4(ny1, nx1, ny2, nx2);
        ws_score[idx] = keep ? bs : -1.0f;
        ws_cls[idx] = best;
    }
}

// ---------------- Kernel B: per-batch sort + greedy NMS walk + top-K ----------------
// Equivalence to the reference:
//  - per-class greedy NMS in (score desc, idx asc) order == a single global
//    walk in (score desc, idx asc) order where a kept box only suppresses
//    same-class boxes (relative order within each class is preserved by the
//    global sort), with the per-class DET_MAX cap (capped classes neither
//    keep nor suppress).
//  - the kept subset, enumerated in global sort order, is exactly the
//    lax.top_k order of sf (= score for kept, -1 otherwise), so output slot
//    = running kept count. Slots >= 100 are dropped; rows beyond the kept
//    count stay zero.
__global__ __launch_bounds__(256) void nms_topk_v2(
    const float* __restrict__ ws_box, const float* __restrict__ ws_score,
    const int* __restrict__ ws_cls, float* __restrict__ out)
{
    const int b = blockIdx.x;
    const int tid = threadIdx.x;

    __shared__ float s_cbox[CMAX][4];        // 16 KB  candidates (unsorted)
    __shared__ float s_csc[CMAX];            //  4 KB
    __shared__ short s_cidx[CMAX];           //  2 KB  original ROI index (tie-break)
    __shared__ unsigned char s_ccls[CMAX];   //  1 KB
    __shared__ float s_sbox[CMAX][4];        // 16 KB  sorted
    __shared__ float s_ssc[CMAX];            //  4 KB
    __shared__ unsigned char s_scls[CMAX];   //  1 KB
    __shared__ unsigned char s_supp[CMAX];   //  1 KB
    __shared__ unsigned char s_kept[CMAX];   //  1 KB
    __shared__ short s_slot[CMAX];           //  2 KB
    __shared__ int s_cnt[NUM_CLASSES];
    __shared__ int s_C;

    if (tid == 0) s_C = 0;
    if (tid < NUM_CLASSES) s_cnt[tid] = 0;

    // zero this batch's output (d_out is poisoned before every replay)
    for (int i = tid; i < DET_MAX * 6; i += 256)
        out[(size_t)b * DET_MAX * 6 + i] = 0.0f;
    __syncthreads();

    // ---- compact candidates (score >= 0) into LDS ----
    for (int i = tid; i < N_ROIS; i += 256) {
        float sc = ws_score[b * N_ROIS + i];
        if (sc >= 0.0f) {
            int k = atomicAdd(&s_C, 1);
            s_csc[k] = sc;
            s_cidx[k] = (short)i;
            s_ccls[k] = (unsigned char)ws_cls[b * N_ROIS + i];
            float4 bb = ((const float4*)ws_box)[b * N_ROIS + i];
            s_cbox[k][0] = bb.x; s_cbox[k][1] = bb.y;
            s_cbox[k][2] = bb.z; s_cbox[k][3] = bb.w;
        }
    }
    __syncthreads();
    const int C = s_C;

    // ---- rank by (score desc, idx asc) and scatter into sorted arrays ----
    // (sc, idx) is a strict total order -> ranks form a permutation of [0,C).
    for (int k = tid; k < C; k += 256) {
        float sk = s_csc[k];
        int ik = s_cidx[k];
        int rank = 0;
        for (int j = 0; j < C; ++j) {   // s_csc[j]/s_cidx[j] are lane-broadcast reads
            float sj = s_csc[j];
            rank += (sj > sk) | ((sj == sk) & (s_cidx[j] < ik));
        }
        s_ssc[rank] = sk;
        s_scls[rank] = s_ccls[k];
        s_sbox[rank][0] = s_cbox[k][0];
        s_sbox[rank][1] = s_cbox[k][1];
        s_sbox[rank][2] = s_cbox[k][2];
        s_sbox[rank][3] = s_cbox[k][3];
        s_supp[rank] = 0;
        s_kept[rank] = 0;
        s_slot[rank] = 0;
    }
    __syncthreads();

    // ---- serial greedy walk (wave 0), lane-parallel suppression ----
    if (tid < 64) {
        int total = 0;
        for (int i = 0; i < C; ++i) {
            if (s_supp[i]) continue;                  // wave-uniform broadcast read
            int c = s_scls[i];
            int cn = s_cnt[c];
            if (cn >= DET_MAX) continue;              // capped: no keep, no suppress
            s_cnt[c] = cn + 1;                        // all lanes write same value
            if (tid == 0) { s_kept[i] = 1; s_slot[i] = (short)total; }
            ++total;
            float a0 = s_sbox[i][0], a1 = s_sbox[i][1];
            float a2 = s_sbox[i][2], a3 = s_sbox[i][3];
            float area_a = (a2 - a0) * (a3 - a1);
            for (int j = i + 1 + tid; j < C; j += 64) {
                if (s_supp[j] || s_scls[j] != c) continue;
                float b0 = s_sbox[j][0], b1 = s_sbox[j][1];
                float b2 = s_sbox[j][2], b3 = s_sbox[j][3];
                float yy1 = fmaxf(a0, b0);
                float xx1 = fmaxf(a1, b1);
                float yy2 = fminf(a2, b2);
                float xx2 = fminf(a3, b3);
                float inter = fmaxf(yy2 - yy1, 0.0f) * fmaxf(xx2 - xx1, 0.0f);
                float area_b = (b2 - b0) * (b3 - b1);
                float uni = area_a + area_b - inter;
                float iou = inter / fmaxf(uni, 1e-10f);
                if (iou > NMS_THRESH) s_supp[j] = 1;
            }
            if (total == DET_MAX) break;   // first 100 kept fully determine output
        }
    }
    __syncthreads();

    // ---- emit: kept order in sorted list == top_k order ----
    for (int i = tid; i < C; i += 256) {
        if (s_kept[i]) {
            int slot = s_slot[i];
            float* o = out + (size_t)b * DET_MAX * 6 + slot * 6;
            o[0] = s_sbox[i][0];
            o[1] = s_sbox[i][1];
            o[2] = s_sbox[i][2];
            o[3] = s_sbox[i][3];
            o[4] = (float)s_scls[i];
            o[5] = s_ssc[i];
        }
    }
}

extern "C" void kernel_launch(void* const* d_in, const int* in_sizes, int n_in,
                              void* d_out, int out_size, void* d_ws, size_t ws_size,
                              hipStream_t stream) {
    const float* rois      = (const float*)d_in[0];
    const float* fpn_class = (const float*)d_in[1];
    const float* fpn_bbox  = (const float*)d_in[2];
    const float* window    = (const float*)d_in[3];
    float* out = (float*)d_out;

    // workspace layout: boxes | scores | class ids  (384 KB total)
    float* ws_box   = (float*)d_ws;                        // BATCH*N_ROIS*4
    float* ws_score = ws_box + (size_t)BATCH * N_ROIS * 4; // BATCH*N_ROIS
    int*   ws_cls   = (int*)(ws_score + (size_t)BATCH * N_ROIS);

    refine_v2<<<BATCH * N_ROIS / ROI_TILE, 256, 0, stream>>>(
        rois, fpn_class, fpn_bbox, window, ws_box, ws_score, ws_cls);
    nms_topk_v2<<<BATCH, 256, 0, stream>>>(ws_box, ws_score, ws_cls, out);
}